// Round 1
// baseline (44.293 us; speedup 1.0000x reference)
//
#include <hip/hip_runtime.h>

#define WINDOW 11
#define H 512
#define W 512
#define OH 502            // H - WINDOW + 1
#define OW 502
#define NCH 3
#define BATCH 8
#define RSTRIPE 8
#define NSTRIPES ((OH + RSTRIPE - 1) / RSTRIPE)   // 63

// per-batch pixel count for the mean: C * OH * OW
#define NPIX_PER_BATCH (3.0f * 502.0f * 502.0f)   // 756012

__global__ __launch_bounds__(256) void ssim_main(const float* __restrict__ x,
                                                 const float* __restrict__ y,
                                                 float* __restrict__ partials) {
    __shared__ float Vx[W], Vy[W], Vxx[W], Vyy[W], Vxy[W];
    __shared__ float red[4];

    const int blk = blockIdx.x;              // b*NCH*NSTRIPES + c*NSTRIPES + s
    const int s   = blk % NSTRIPES;
    const int img = blk / NSTRIPES;          // b*NCH + c
    const float* __restrict__ xi = x + (size_t)img * H * W;
    const float* __restrict__ yi = y + (size_t)img * H * W;
    const int t  = threadIdx.x;
    const int i0 = s * RSTRIPE;
    const int i1 = min(i0 + RSTRIPE, OH);

    // --- init vertical column sums for output row i0 (rows i0..i0+10) ---
    for (int j = t; j < W; j += 256) {
        float sx = 0.f, sy = 0.f, sxx = 0.f, syy = 0.f, sxy = 0.f;
#pragma unroll
        for (int r = 0; r < WINDOW; ++r) {
            float a = xi[(i0 + r) * W + j];
            float b = yi[(i0 + r) * W + j];
            sx += a; sy += b;
            sxx += a * a; syy += b * b; sxy += a * b;
        }
        Vx[j] = sx; Vy[j] = sy; Vxx[j] = sxx; Vyy[j] = syy; Vxy[j] = sxy;
    }

    const float n       = 121.0f;
    const float inv_n   = 1.0f / 121.0f;
    const float inv_nm1 = 1.0f / 120.0f;
    const float c1 = 1e-4f;   // (0.01)^2
    const float c2 = 9e-4f;   // (0.03)^2

    float acc = 0.f;
    for (int i = i0;;) {
        __syncthreads();   // column sums for row i are visible

        // --- horizontal 11-tap window sums + SSIM for output row i ---
        for (int j = t; j < OW; j += 256) {
            float sx = 0.f, sy = 0.f, sxx = 0.f, syy = 0.f, sxy = 0.f;
#pragma unroll
            for (int k = 0; k < WINDOW; ++k) {
                sx  += Vx[j + k];
                sy  += Vy[j + k];
                sxx += Vxx[j + k];
                syy += Vyy[j + k];
                sxy += Vxy[j + k];
            }
            float mx  = sx * inv_n;
            float my  = sy * inv_n;
            float vx  = (sxx - n * mx * mx) * inv_nm1;
            float vy  = (syy - n * my * my) * inv_nm1;
            float cov = (sxy - n * mx * my) * inv_nm1;
            float ssim = (2.f * mx * my + c1) * (2.f * cov + c2) /
                         ((mx * mx + my * my + c1) * (vx + vy + c2));
            acc += ssim;
        }

        ++i;
        if (i >= i1) break;

        __syncthreads();   // all reads of V* done before we mutate them

        // --- slide: remove row (i-1), add row (i+10) ---
        for (int j = t; j < W; j += 256) {
            float ao = xi[(i - 1) * W + j];
            float bo = yi[(i - 1) * W + j];
            float an = xi[(i + 10) * W + j];
            float bn = yi[(i + 10) * W + j];
            Vx[j]  += an - ao;
            Vy[j]  += bn - bo;
            Vxx[j] += an * an - ao * ao;
            Vyy[j] += bn * bn - bo * bo;
            Vxy[j] += an * bn - ao * bo;
        }
    }

    // --- block reduction of acc (fixed-order, deterministic) ---
    for (int off = 32; off > 0; off >>= 1)
        acc += __shfl_down(acc, off, 64);
    int wid = t >> 6, lane = t & 63;
    if (lane == 0) red[wid] = acc;
    __syncthreads();
    if (t == 0)
        partials[blk] = (red[0] + red[1]) + (red[2] + red[3]);
}

__global__ __launch_bounds__(256) void ssim_reduce(const float* __restrict__ partials,
                                                   float* __restrict__ out) {
    const int b = blockIdx.x;       // one block per batch element
    const int t = threadIdx.x;
    const int per = NCH * NSTRIPES; // 189 partials per batch
    float s = 0.f;
    for (int k = t; k < per; k += 256)
        s += partials[b * per + k];
    for (int off = 32; off > 0; off >>= 1)
        s += __shfl_down(s, off, 64);
    __shared__ float red[4];
    int wid = t >> 6, lane = t & 63;
    if (lane == 0) red[wid] = s;
    __syncthreads();
    if (t == 0) {
        float tot = (red[0] + red[1]) + (red[2] + red[3]);
        out[b] = (1.0f - tot / NPIX_PER_BATCH) * 0.5f;
    }
}

extern "C" void kernel_launch(void* const* d_in, const int* in_sizes, int n_in,
                              void* d_out, int out_size, void* d_ws, size_t ws_size,
                              hipStream_t stream) {
    const float* x = (const float*)d_in[0];
    const float* y = (const float*)d_in[1];
    float* out      = (float*)d_out;
    float* partials = (float*)d_ws;   // 1512 floats, fully overwritten each call

    const int nblocks = BATCH * NCH * NSTRIPES;   // 1512
    ssim_main<<<nblocks, 256, 0, stream>>>(x, y, partials);
    ssim_reduce<<<BATCH, 256, 0, stream>>>(partials, out);
}

// Round 2
// 36.784 us; speedup vs baseline: 1.2041x; 1.2041x over previous
//
#include <hip/hip_runtime.h>

#define WINDOW 11
#define H 512
#define W 512
#define OH 502            // H - WINDOW + 1
#define OW 502
#define NCH 3
#define BATCH 8
#define RSTRIPE 16
#define NSTRIPES 32       // ceil(502/16)

#define NPIX_PER_BATCH (3.0f * 502.0f * 502.0f)   // 756012

// XOR swizzle on float4 index: bijective involution (bits 0-2 ^= bits 3-5),
// spreads the 32B-stride lane pattern across all 8 LDS bank-groups.
__device__ __forceinline__ int sw(int j) { return j ^ ((j >> 3) & 7); }

__device__ __forceinline__ float ssim_from(float4 s) {
    const float n = 121.0f;
    const float inv_n = 1.0f / 121.0f;
    const float inv_nm1 = 1.0f / 120.0f;
    const float c1 = 1e-4f;   // (0.01)^2
    const float c2 = 9e-4f;   // (0.03)^2
    float mx  = s.x * inv_n;
    float my  = s.y * inv_n;
    float mxy = mx * my;
    float m2  = mx * mx + my * my;
    float cov = (s.w - n * mxy) * inv_nm1;   // covariance
    float v2  = (s.z - n * m2)  * inv_nm1;   // vx + vy
    return (2.f * mxy + c1) * (2.f * cov + c2) /
           ((m2 + c1) * (v2 + c2));
}

__global__ __launch_bounds__(256) void ssim_main(const float* __restrict__ x,
                                                 const float* __restrict__ y,
                                                 float* __restrict__ partials) {
    __shared__ float4 V4[512];   // per-column {sx, sy, sxx+syy, sxy}, swizzled
    __shared__ float red[4];

    const int blk = blockIdx.x;              // img*NSTRIPES + s
    const int s   = blk % NSTRIPES;
    const int img = blk / NSTRIPES;          // b*NCH + c
    const float* __restrict__ xi = x + (size_t)img * H * W;
    const float* __restrict__ yi = y + (size_t)img * H * W;
    const int t  = threadIdx.x;
    const int i0 = s * RSTRIPE;
    const int i1 = min(i0 + RSTRIPE, OH);

    // --- init vertical column sums for output row i0 (rows i0..i0+10) ---
    for (int j = t; j < W; j += 256) {
        float sx = 0.f, sy = 0.f, s2 = 0.f, sxy = 0.f;
#pragma unroll
        for (int r = 0; r < WINDOW; ++r) {
            float a = xi[(i0 + r) * W + j];
            float b = yi[(i0 + r) * W + j];
            sx += a; sy += b;
            s2 += a * a + b * b;
            sxy += a * b;
        }
        V4[sw(j)] = make_float4(sx, sy, s2, sxy);
    }

    const int  j0     = 2 * t;          // thread owns output cols j0, j0+1
    const bool active = (j0 < OW);      // OW even -> both cols valid

    float acc = 0.f;
    for (int i = i0;;) {
        __syncthreads();   // column sums for row i visible

        if (active) {
            // 11-tap horizontal sum for col j0, slide +1 tap for col j0+1
            float4 t0  = V4[sw(j0)];
            float4 sum = t0;
#pragma unroll
            for (int k = 1; k < WINDOW; ++k) {
                float4 v = V4[sw(j0 + k)];
                sum.x += v.x; sum.y += v.y; sum.z += v.z; sum.w += v.w;
            }
            acc += ssim_from(sum);
            float4 t11 = V4[sw(j0 + WINDOW)];
            sum.x += t11.x - t0.x;
            sum.y += t11.y - t0.y;
            sum.z += t11.z - t0.z;
            sum.w += t11.w - t0.w;
            acc += ssim_from(sum);
        }

        ++i;
        if (i >= i1) break;

        __syncthreads();   // all tap reads done before mutating V4

        // --- slide: remove input row (i-1), add input row (i+10) ---
        for (int j = t; j < W; j += 256) {
            float ao = xi[(i - 1) * W + j];
            float bo = yi[(i - 1) * W + j];
            float an = xi[(i + 10) * W + j];
            float bn = yi[(i + 10) * W + j];
            float4 v = V4[sw(j)];
            v.x += an - ao;
            v.y += bn - bo;
            v.z += an * an + bn * bn - ao * ao - bo * bo;
            v.w += an * bn - ao * bo;
            V4[sw(j)] = v;
        }
    }

    // --- block reduction (fixed order, deterministic) ---
    for (int off = 32; off > 0; off >>= 1)
        acc += __shfl_down(acc, off, 64);
    int wid = t >> 6, lane = t & 63;
    if (lane == 0) red[wid] = acc;
    __syncthreads();
    if (t == 0)
        partials[blk] = (red[0] + red[1]) + (red[2] + red[3]);
}

__global__ __launch_bounds__(256) void ssim_reduce(const float* __restrict__ partials,
                                                   float* __restrict__ out) {
    const int b = blockIdx.x;         // one block per batch element
    const int t = threadIdx.x;
    const int per = NCH * NSTRIPES;   // 96 partials per batch
    float s = 0.f;
    for (int k = t; k < per; k += 256)
        s += partials[b * per + k];
    for (int off = 32; off > 0; off >>= 1)
        s += __shfl_down(s, off, 64);
    __shared__ float red[4];
    int wid = t >> 6, lane = t & 63;
    if (lane == 0) red[wid] = s;
    __syncthreads();
    if (t == 0) {
        float tot = (red[0] + red[1]) + (red[2] + red[3]);
        out[b] = (1.0f - tot / NPIX_PER_BATCH) * 0.5f;
    }
}

extern "C" void kernel_launch(void* const* d_in, const int* in_sizes, int n_in,
                              void* d_out, int out_size, void* d_ws, size_t ws_size,
                              hipStream_t stream) {
    const float* x = (const float*)d_in[0];
    const float* y = (const float*)d_in[1];
    float* out      = (float*)d_out;
    float* partials = (float*)d_ws;   // 768 floats, fully overwritten each call

    const int nblocks = BATCH * NCH * NSTRIPES;   // 768
    ssim_main<<<nblocks, 256, 0, stream>>>(x, y, partials);
    ssim_reduce<<<BATCH, 256, 0, stream>>>(partials, out);
}